// Round 1
// baseline (448.576 us; speedup 1.0000x reference)
//
#include <hip/hip_runtime.h>
#include <hip/hip_cooperative_groups.h>
#include <math.h>

namespace cg = cooperative_groups;

// Problem constants: B=8, C=256, H=W=128
#define NPLANE 2048
#define HW     16384
#define WW     128
#define SLOPE  0.01f
#define EPS    1e-5f

typedef float v4f __attribute__((ext_vector_type(4)));  // native vec for nontemporal store

// Load one image row segment (4 cols) + left/right neighbors via cross-lane
// shuffle.  Lanes 0-31 of a wave span one full row (32*4=128 cols); lanes
// 32-63 span another row, so the lane-31/32 shuffle boundary coincides with
// the column zero-pad boundary -- one mask handles both.
__device__ __forceinline__ void load_row(const float* __restrict__ xp, int r,
                                         int c4, int lane32,
                                         float4& m, float& L, float& R) {
    int rc = r;
    if (rc < 0) rc = 0;
    if (rc > 127) rc = 127;
    const float va = (r == rc) ? 1.f : 0.f;        // zero-pad rows -1 / 128
    float4 v = *(const float4*)(xp + rc * WW + c4);
    m.x = v.x * va; m.y = v.y * va; m.z = v.z * va; m.w = v.w * va;
    L = __shfl_up(m.w, 1, 64);
    if (lane32 == 0) L = 0.f;                      // col -1 zero-pad
    R = __shfl_down(m.x, 1, 64);
    if (lane32 == 31) R = 0.f;                     // col 128 zero-pad
}

#define CONV4(o0, o1, o2, o3)                                                \
    float o0 = w_0*L0   + w_1*m0.x + w_2*m0.y                                \
             + w_3*L1   + w_4*m1.x + w_5*m1.y                                \
             + w_6*L2   + w_7*m2.x + w_8*m2.y;                               \
    float o1 = w_0*m0.x + w_1*m0.y + w_2*m0.z                                \
             + w_3*m1.x + w_4*m1.y + w_5*m1.z                                \
             + w_6*m2.x + w_7*m2.y + w_8*m2.z;                               \
    float o2 = w_0*m0.y + w_1*m0.z + w_2*m0.w                                \
             + w_3*m1.y + w_4*m1.z + w_5*m1.w                                \
             + w_6*m2.y + w_7*m2.z + w_8*m2.w;                               \
    float o3 = w_0*m0.z + w_1*m0.w + w_2*R0                                  \
             + w_3*m1.z + w_4*m1.w + w_5*R1                                  \
             + w_6*m2.z + w_7*m2.w + w_8*R2

#define SLIDE() do { m0 = m1; L0 = L1; R0 = R1; m1 = m2; L1 = L2; R1 = R2; } while (0)

// ---------------------------------------------------------------------------
// Fused cooperative kernel:
//   phase 1: one streaming read of x -> plane mean (attention input),
//            conv-sum, conv-sumsq (folded inst-norm stats).
//   grid-wide sync (p must be complete across ALL channels of each batch).
//   phase 2: per-plane attention MLP + conv + folded inst-norm + leaky,
//            single streaming pass (x L3-resident from phase 1).
//     out = a*(conv - mean_c) * rsqrt(a^2*var_c + eps); bias cancels exactly.
// 2048 blocks x 256 thr = exactly 8 blocks/CU on 256 CUs; launch_bounds(256,8)
// caps VGPRs at 64 so the cooperative grid is fully co-resident.
// ---------------------------------------------------------------------------
__global__ __launch_bounds__(256, 8) void k_fused(const float* __restrict__ x,
                                                  const float* __restrict__ w1,
                                                  const float* __restrict__ w2,
                                                  const float* __restrict__ rw,
                                                  float* __restrict__ p,
                                                  float* __restrict__ cstats,
                                                  float* __restrict__ out) {
    __shared__ float red[12];
    __shared__ float hs[64];
    __shared__ float sh_mean, sh_scale;

    const int plane = blockIdx.x;
    const int b = plane >> 8, ch = plane & 255;
    const float* xp = x + (size_t)plane * HW;
    const int lane32 = threadIdx.x & 31;
    const int c4 = lane32 * 4;
    const int r0 = (threadIdx.x >> 5) * 16;

    const float w_0 = rw[ch*9+0], w_1 = rw[ch*9+1], w_2 = rw[ch*9+2];
    const float w_3 = rw[ch*9+3], w_4 = rw[ch*9+4], w_5 = rw[ch*9+5];
    const float w_6 = rw[ch*9+6], w_7 = rw[ch*9+7], w_8 = rw[ch*9+8];

    // ---------------- phase 1: stats ----------------
    {
        float4 m0, m1, m2;
        float L0, R0, L1, R1, L2, R2;
        load_row(xp, r0 - 1, c4, lane32, m0, L0, R0);
        load_row(xp, r0,     c4, lane32, m1, L1, R1);

        float xs = 0.f, s = 0.f, sq = 0.f;
#pragma unroll 4
        for (int j = 0; j < 16; ++j) {
            load_row(xp, r0 + j + 1, c4, lane32, m2, L2, R2);
            CONV4(o0, o1, o2, o3);
            s  += (o0 + o1) + (o2 + o3);
            sq += o0*o0 + o1*o1 + o2*o2 + o3*o3;
            xs += (m1.x + m1.y) + (m1.z + m1.w);   // row r counted exactly once
            SLIDE();
        }

#pragma unroll
        for (int off = 32; off; off >>= 1) {
            xs += __shfl_down(xs, off, 64);
            s  += __shfl_down(s,  off, 64);
            sq += __shfl_down(sq, off, 64);
        }
        const int wave = threadIdx.x >> 6, lane = threadIdx.x & 63;
        if (lane == 0) { red[wave] = xs; red[4+wave] = s; red[8+wave] = sq; }
        __syncthreads();
        if (threadIdx.x == 0) {
            p[plane]            = ((red[0]+red[1]) + (red[2]+red[3])) * (1.f/(float)HW);
            cstats[plane*2]     = (red[4]+red[5]) + (red[6]+red[7]);
            cstats[plane*2 + 1] = (red[8]+red[9]) + (red[10]+red[11]);
        }
    }

    // p[b,:] must be complete for every batch before any attention MLP runs.
    cg::this_grid().sync();

    // ---------------- phase 2: attention + output ----------------
    // attention hidden layer: hs[j] = leaky(dot(p[b,:], w1[j,:])), 4 thr/j
    {
        const int j = threadIdx.x >> 2, part = threadIdx.x & 3;
        const float4* pr = (const float4*)(p  + b * 256 + part * 64);
        const float4* wr = (const float4*)(w1 + j * 256 + part * 64);
        float acc = 0.f;
#pragma unroll
        for (int k = 0; k < 16; ++k) {
            float4 pv = pr[k], wv = wr[k];
            acc += pv.x*wv.x + pv.y*wv.y + pv.z*wv.z + pv.w*wv.w;
        }
        acc += __shfl_xor(acc, 1, 64);
        acc += __shfl_xor(acc, 2, 64);
        if (part == 0) hs[j] = acc > 0.f ? acc : SLOPE * acc;
    }
    __syncthreads();
    if (threadIdx.x < 64) {
        float v = w2[ch * 64 + threadIdx.x] * hs[threadIdx.x];
#pragma unroll
        for (int off = 32; off; off >>= 1) v += __shfl_down(v, off, 64);
        if (threadIdx.x == 0) {
            const float a  = 1.f / (1.f + expf(-v));
            const float mc = cstats[plane*2] * (1.f/(float)HW);
            const float vc = cstats[plane*2 + 1] * (1.f/(float)HW) - mc * mc;
            sh_mean  = mc;
            sh_scale = a * rsqrtf(a * a * vc + EPS);
        }
    }
    __syncthreads();
    const float mean_c = sh_mean, scale = sh_scale;

    float* op = out + (size_t)plane * HW;
    {
        float4 m0, m1, m2;
        float L0, R0, L1, R1, L2, R2;
        load_row(xp, r0 - 1, c4, lane32, m0, L0, R0);
        load_row(xp, r0,     c4, lane32, m1, L1, R1);

#pragma unroll 4
        for (int j = 0; j < 16; ++j) {
            load_row(xp, r0 + j + 1, c4, lane32, m2, L2, R2);
            CONV4(o0, o1, o2, o3);
            v4f res;
            float t0 = scale * (o0 - mean_c); res.x = t0 > 0.f ? t0 : SLOPE * t0;
            float t1 = scale * (o1 - mean_c); res.y = t1 > 0.f ? t1 : SLOPE * t1;
            float t2 = scale * (o2 - mean_c); res.z = t2 > 0.f ? t2 : SLOPE * t2;
            float t3 = scale * (o3 - mean_c); res.w = t3 > 0.f ? t3 : SLOPE * t3;
            __builtin_nontemporal_store(res, (v4f*)(op + (r0 + j) * WW + c4));
            SLIDE();
        }
    }
}

// ---------------------------------------------------------------------------
// Fallback path (identical to previous best) in case the cooperative launch
// is rejected (e.g. occupancy validation fails) -- keeps us at baseline.
// ---------------------------------------------------------------------------
__global__ __launch_bounds__(256, 8) void k_stats(const float* __restrict__ x,
                                                  const float* __restrict__ rw,
                                                  float* __restrict__ p,
                                                  float* __restrict__ cstats) {
    const int plane = blockIdx.x;
    const int ch = plane & 255;
    const float* xp = x + (size_t)plane * HW;
    const int lane32 = threadIdx.x & 31;
    const int c4 = lane32 * 4;
    const int r0 = (threadIdx.x >> 5) * 16;

    const float w_0 = rw[ch*9+0], w_1 = rw[ch*9+1], w_2 = rw[ch*9+2];
    const float w_3 = rw[ch*9+3], w_4 = rw[ch*9+4], w_5 = rw[ch*9+5];
    const float w_6 = rw[ch*9+6], w_7 = rw[ch*9+7], w_8 = rw[ch*9+8];

    float4 m0, m1, m2;
    float L0, R0, L1, R1, L2, R2;
    load_row(xp, r0 - 1, c4, lane32, m0, L0, R0);
    load_row(xp, r0,     c4, lane32, m1, L1, R1);

    float xs = 0.f, s = 0.f, sq = 0.f;
#pragma unroll 4
    for (int j = 0; j < 16; ++j) {
        load_row(xp, r0 + j + 1, c4, lane32, m2, L2, R2);
        CONV4(o0, o1, o2, o3);
        s  += (o0 + o1) + (o2 + o3);
        sq += o0*o0 + o1*o1 + o2*o2 + o3*o3;
        xs += (m1.x + m1.y) + (m1.z + m1.w);
        SLIDE();
    }

#pragma unroll
    for (int off = 32; off; off >>= 1) {
        xs += __shfl_down(xs, off, 64);
        s  += __shfl_down(s,  off, 64);
        sq += __shfl_down(sq, off, 64);
    }
    __shared__ float red[12];
    const int wave = threadIdx.x >> 6, lane = threadIdx.x & 63;
    if (lane == 0) { red[wave] = xs; red[4+wave] = s; red[8+wave] = sq; }
    __syncthreads();
    if (threadIdx.x == 0) {
        p[plane]            = ((red[0]+red[1]) + (red[2]+red[3])) * (1.f/(float)HW);
        cstats[plane*2]     = (red[4]+red[5]) + (red[6]+red[7]);
        cstats[plane*2 + 1] = (red[8]+red[9]) + (red[10]+red[11]);
    }
}

__global__ __launch_bounds__(256, 8) void k_out(const float* __restrict__ x,
                                                const float* __restrict__ w1,
                                                const float* __restrict__ w2,
                                                const float* __restrict__ rw,
                                                const float* __restrict__ p,
                                                const float* __restrict__ cstats,
                                                float* __restrict__ out) {
    __shared__ float hs[64];
    __shared__ float sh_mean, sh_scale;
    const int plane = blockIdx.x;
    const int b = plane >> 8, ch = plane & 255;

    {
        const int j = threadIdx.x >> 2, part = threadIdx.x & 3;
        const float4* pr = (const float4*)(p  + b * 256 + part * 64);
        const float4* wr = (const float4*)(w1 + j * 256 + part * 64);
        float acc = 0.f;
#pragma unroll
        for (int k = 0; k < 16; ++k) {
            float4 pv = pr[k], wv = wr[k];
            acc += pv.x*wv.x + pv.y*wv.y + pv.z*wv.z + pv.w*wv.w;
        }
        acc += __shfl_xor(acc, 1, 64);
        acc += __shfl_xor(acc, 2, 64);
        if (part == 0) hs[j] = acc > 0.f ? acc : SLOPE * acc;
    }
    __syncthreads();
    if (threadIdx.x < 64) {
        float v = w2[ch * 64 + threadIdx.x] * hs[threadIdx.x];
#pragma unroll
        for (int off = 32; off; off >>= 1) v += __shfl_down(v, off, 64);
        if (threadIdx.x == 0) {
            const float a  = 1.f / (1.f + expf(-v));
            const float mc = cstats[plane*2] * (1.f/(float)HW);
            const float vc = cstats[plane*2 + 1] * (1.f/(float)HW) - mc * mc;
            sh_mean  = mc;
            sh_scale = a * rsqrtf(a * a * vc + EPS);
        }
    }

    const float w_0 = rw[ch*9+0], w_1 = rw[ch*9+1], w_2 = rw[ch*9+2];
    const float w_3 = rw[ch*9+3], w_4 = rw[ch*9+4], w_5 = rw[ch*9+5];
    const float w_6 = rw[ch*9+6], w_7 = rw[ch*9+7], w_8 = rw[ch*9+8];

    __syncthreads();
    const float mean_c = sh_mean, scale = sh_scale;

    const float* xp = x + (size_t)plane * HW;
    float* op = out + (size_t)plane * HW;
    const int lane32 = threadIdx.x & 31;
    const int c4 = lane32 * 4;
    const int r0 = (threadIdx.x >> 5) * 16;

    float4 m0, m1, m2;
    float L0, R0, L1, R1, L2, R2;
    load_row(xp, r0 - 1, c4, lane32, m0, L0, R0);
    load_row(xp, r0,     c4, lane32, m1, L1, R1);

#pragma unroll 4
    for (int j = 0; j < 16; ++j) {
        load_row(xp, r0 + j + 1, c4, lane32, m2, L2, R2);
        CONV4(o0, o1, o2, o3);
        v4f res;
        float t0 = scale * (o0 - mean_c); res.x = t0 > 0.f ? t0 : SLOPE * t0;
        float t1 = scale * (o1 - mean_c); res.y = t1 > 0.f ? t1 : SLOPE * t1;
        float t2 = scale * (o2 - mean_c); res.z = t2 > 0.f ? t2 : SLOPE * t2;
        float t3 = scale * (o3 - mean_c); res.w = t3 > 0.f ? t3 : SLOPE * t3;
        __builtin_nontemporal_store(res, (v4f*)(op + (r0 + j) * WW + c4));
        SLIDE();
    }
}

// ---------------------------------------------------------------------------
extern "C" void kernel_launch(void* const* d_in, const int* in_sizes, int n_in,
                              void* d_out, int out_size, void* d_ws, size_t ws_size,
                              hipStream_t stream) {
    const float* x  = (const float*)d_in[0];
    const float* w1 = (const float*)d_in[1];   // [64,256]
    const float* w2 = (const float*)d_in[2];   // [256,64]
    const float* rw = (const float*)d_in[3];   // [256,1,3,3]
    // d_in[4] (refine_b) cancels exactly in instance norm -- unused.
    float* out = (float*)d_out;

    float* p      = (float*)d_ws;       // 2048 floats
    float* cstats = p + NPLANE;         // 4096 floats (sum, sumsq per plane)

    void* args[] = {(void*)&x, (void*)&w1, (void*)&w2, (void*)&rw,
                    (void*)&p, (void*)&cstats, (void*)&out};
    hipError_t e = hipLaunchCooperativeKernel((const void*)k_fused,
                                              dim3(NPLANE), dim3(256),
                                              args, 0, stream);
    if (e != hipSuccess) {
        // occupancy/validation rejection -> previous-best two-kernel path
        k_stats<<<NPLANE, 256, 0, stream>>>(x, rw, p, cstats);
        k_out  <<<NPLANE, 256, 0, stream>>>(x, w1, w2, rw, p, cstats, out);
    }
}

// Round 3
// 360.241 us; speedup vs baseline: 1.2452x; 1.2452x over previous
//
#include <hip/hip_runtime.h>
#include <math.h>

// Problem constants: B=8, C=256, H=W=128
#define NPLANE 2048
#define HW     16384
#define WW     128
#define SLOPE  0.01f
#define EPS    1e-5f

typedef float v4f __attribute__((ext_vector_type(4)));  // native vec for nontemporal store

struct W9 { float w0,w1,w2,w3,w4,w5,w6,w7,w8; };

// ---------------------------------------------------------------------------
// Burst-batch conv over 8 output rows (rows rbase..rbase+7 of the plane).
// Structure chosen for memory pipelining (round-1 diagnosis: the old SLIDE()
// sliding window let the compiler keep only ~2 loads in flight -> vmcnt
// latency bound at VALUBusy ~10%, HBM ~13-27%):
//   1) burst-load 10 raw rows (no dependent VALU in the load loop),
//   2) zero-mask only the two possibly-out-of-range rows,
//   3) batch ALL 20 halo shuffles (single lgkm drain),
//   4) pure-VALU conv loop over statically-indexed arrays (no scratch).
// Lanes 0-31 of a wave span one full row (32*4=128 cols); the lane-31/32
// shuffle boundary coincides with the column zero-pad boundary.
// Register budget: raw 40 + Lh/Rh 20 + acc/addr ~13 => ~73 VGPR, fits the
// __launch_bounds__(256,6) cap (~84) without spilling.
// ---------------------------------------------------------------------------
template<bool DO_STATS, bool DO_STORE>
__device__ __forceinline__ void conv_batch8(const float* __restrict__ xp,
                                            float* __restrict__ op,
                                            int rbase, int c4, int lane32,
                                            const W9 w, float scale, float mean_c,
                                            float& xs, float& s, float& sq) {
    float4 raw[10];
    float  Lh[10], Rh[10];
#pragma unroll
    for (int t = 0; t < 10; ++t) {
        int r  = rbase + t - 1;
        int rc = r < 0 ? 0 : (r > 127 ? 127 : r);
        raw[t] = *(const float4*)(xp + rc * WW + c4);
    }
    if (rbase - 1 < 0)
        { raw[0].x = 0.f; raw[0].y = 0.f; raw[0].z = 0.f; raw[0].w = 0.f; }
    if (rbase + 8 > 127)
        { raw[9].x = 0.f; raw[9].y = 0.f; raw[9].z = 0.f; raw[9].w = 0.f; }
#pragma unroll
    for (int t = 0; t < 10; ++t) {
        Lh[t] = __shfl_up(raw[t].w, 1, 64);
        Rh[t] = __shfl_down(raw[t].x, 1, 64);
    }
    if (lane32 == 0) {
#pragma unroll
        for (int t = 0; t < 10; ++t) Lh[t] = 0.f;
    }
    if (lane32 == 31) {
#pragma unroll
        for (int t = 0; t < 10; ++t) Rh[t] = 0.f;
    }
#pragma unroll
    for (int j = 0; j < 8; ++j) {
        float o0 = w.w0*Lh[j]       + w.w1*raw[j].x    + w.w2*raw[j].y
                 + w.w3*Lh[j+1]     + w.w4*raw[j+1].x  + w.w5*raw[j+1].y
                 + w.w6*Lh[j+2]     + w.w7*raw[j+2].x  + w.w8*raw[j+2].y;
        float o1 = w.w0*raw[j].x    + w.w1*raw[j].y    + w.w2*raw[j].z
                 + w.w3*raw[j+1].x  + w.w4*raw[j+1].y  + w.w5*raw[j+1].z
                 + w.w6*raw[j+2].x  + w.w7*raw[j+2].y  + w.w8*raw[j+2].z;
        float o2 = w.w0*raw[j].y    + w.w1*raw[j].z    + w.w2*raw[j].w
                 + w.w3*raw[j+1].y  + w.w4*raw[j+1].z  + w.w5*raw[j+1].w
                 + w.w6*raw[j+2].y  + w.w7*raw[j+2].z  + w.w8*raw[j+2].w;
        float o3 = w.w0*raw[j].z    + w.w1*raw[j].w    + w.w2*Rh[j]
                 + w.w3*raw[j+1].z  + w.w4*raw[j+1].w  + w.w5*Rh[j+1]
                 + w.w6*raw[j+2].z  + w.w7*raw[j+2].w  + w.w8*Rh[j+2];
        if constexpr (DO_STATS) {
            s  += (o0 + o1) + (o2 + o3);
            sq += o0*o0 + o1*o1 + o2*o2 + o3*o3;
            xs += (raw[j+1].x + raw[j+1].y) + (raw[j+1].z + raw[j+1].w);
        }
        if constexpr (DO_STORE) {
            v4f res;
            float t0 = scale*(o0 - mean_c); res.x = t0 > 0.f ? t0 : SLOPE*t0;
            float t1 = scale*(o1 - mean_c); res.y = t1 > 0.f ? t1 : SLOPE*t1;
            float t2 = scale*(o2 - mean_c); res.z = t2 > 0.f ? t2 : SLOPE*t2;
            float t3 = scale*(o3 - mean_c); res.w = t3 > 0.f ? t3 : SLOPE*t3;
            __builtin_nontemporal_store(res, (v4f*)(op + (rbase + j) * WW + c4));
        }
    }
}

// ---------------------------------------------------------------------------
// Kernel A: ONE streaming read of x computing, per plane:
//   plane mean (for attention), conv-sum, conv-sumsq (for folded inst-norm).
// Thread t: columns [4*(t&31), +4), row strip [16*(t>>5), +16), processed as
// two burst batches of 8 rows.
// ---------------------------------------------------------------------------
__global__ __launch_bounds__(256, 6) void k_stats(const float* __restrict__ x,
                                                  const float* __restrict__ rw,
                                                  float* __restrict__ p,
                                                  float* __restrict__ cstats) {
    const int plane = blockIdx.x;
    const int ch = plane & 255;
    const float* xp = x + (size_t)plane * HW;
    const int lane32 = threadIdx.x & 31;
    const int c4 = lane32 * 4;
    const int r0 = (threadIdx.x >> 5) * 16;

    const W9 w = { rw[ch*9+0], rw[ch*9+1], rw[ch*9+2],
                   rw[ch*9+3], rw[ch*9+4], rw[ch*9+5],
                   rw[ch*9+6], rw[ch*9+7], rw[ch*9+8] };

    float xs = 0.f, s = 0.f, sq = 0.f;
    conv_batch8<true, false>(xp, nullptr, r0,     c4, lane32, w, 0.f, 0.f, xs, s, sq);
    conv_batch8<true, false>(xp, nullptr, r0 + 8, c4, lane32, w, 0.f, 0.f, xs, s, sq);

#pragma unroll
    for (int off = 32; off; off >>= 1) {
        xs += __shfl_down(xs, off, 64);
        s  += __shfl_down(s,  off, 64);
        sq += __shfl_down(sq, off, 64);
    }
    __shared__ float red[12];
    const int wave = threadIdx.x >> 6, lane = threadIdx.x & 63;
    if (lane == 0) { red[wave] = xs; red[4+wave] = s; red[8+wave] = sq; }
    __syncthreads();
    if (threadIdx.x == 0) {
        p[plane]            = ((red[0]+red[1]) + (red[2]+red[3])) * (1.f/(float)HW);
        cstats[plane*2]     = (red[4]+red[5]) + (red[6]+red[7]);
        cstats[plane*2 + 1] = (red[8]+red[9]) + (red[10]+red[11]);
    }
}

// ---------------------------------------------------------------------------
// Kernel B: attention MLP (tiny, per-block) + conv + folded instance-norm +
// leaky, single streaming pass (x is L2/L3-resident from kernel A).
//   out = a*(conv - mean_c) * rsqrt(a^2*var_c + eps); bias cancels exactly.
// ---------------------------------------------------------------------------
__global__ __launch_bounds__(256, 6) void k_out(const float* __restrict__ x,
                                                const float* __restrict__ w1,
                                                const float* __restrict__ w2,
                                                const float* __restrict__ rw,
                                                const float* __restrict__ p,
                                                const float* __restrict__ cstats,
                                                float* __restrict__ out) {
    __shared__ float hs[64];
    __shared__ float sh_mean, sh_scale;
    const int plane = blockIdx.x;
    const int b = plane >> 8, ch = plane & 255;

    // attention hidden layer: hs[j] = leaky(dot(p[b,:], w1[j,:])), 4 thr/j
    {
        const int j = threadIdx.x >> 2, part = threadIdx.x & 3;
        const float4* pr = (const float4*)(p  + b * 256 + part * 64);
        const float4* wr = (const float4*)(w1 + j * 256 + part * 64);
        float acc = 0.f;
#pragma unroll
        for (int k = 0; k < 16; ++k) {
            float4 pv = pr[k], wv = wr[k];
            acc += pv.x*wv.x + pv.y*wv.y + pv.z*wv.z + pv.w*wv.w;
        }
        acc += __shfl_xor(acc, 1, 64);
        acc += __shfl_xor(acc, 2, 64);
        if (part == 0) hs[j] = acc > 0.f ? acc : SLOPE * acc;
    }
    __syncthreads();
    if (threadIdx.x < 64) {
        float v = w2[ch * 64 + threadIdx.x] * hs[threadIdx.x];
#pragma unroll
        for (int off = 32; off; off >>= 1) v += __shfl_down(v, off, 64);
        if (threadIdx.x == 0) {
            const float a  = 1.f / (1.f + expf(-v));
            const float mc = cstats[plane*2] * (1.f/(float)HW);
            const float vc = cstats[plane*2 + 1] * (1.f/(float)HW) - mc * mc;
            sh_mean  = mc;
            sh_scale = a * rsqrtf(a * a * vc + EPS);
        }
    }

    const W9 w = { rw[ch*9+0], rw[ch*9+1], rw[ch*9+2],
                   rw[ch*9+3], rw[ch*9+4], rw[ch*9+5],
                   rw[ch*9+6], rw[ch*9+7], rw[ch*9+8] };

    __syncthreads();
    const float mean_c = sh_mean, scale = sh_scale;

    const float* xp = x + (size_t)plane * HW;
    float* op = out + (size_t)plane * HW;
    const int lane32 = threadIdx.x & 31;
    const int c4 = lane32 * 4;
    const int r0 = (threadIdx.x >> 5) * 16;

    float xs, s, sq;  // unused in store path
    conv_batch8<false, true>(xp, op, r0,     c4, lane32, w, scale, mean_c, xs, s, sq);
    conv_batch8<false, true>(xp, op, r0 + 8, c4, lane32, w, scale, mean_c, xs, s, sq);
}

// ---------------------------------------------------------------------------
extern "C" void kernel_launch(void* const* d_in, const int* in_sizes, int n_in,
                              void* d_out, int out_size, void* d_ws, size_t ws_size,
                              hipStream_t stream) {
    const float* x  = (const float*)d_in[0];
    const float* w1 = (const float*)d_in[1];   // [64,256]
    const float* w2 = (const float*)d_in[2];   // [256,64]
    const float* rw = (const float*)d_in[3];   // [256,1,3,3]
    // d_in[4] (refine_b) cancels exactly in instance norm -- unused.
    float* out = (float*)d_out;

    float* p      = (float*)d_ws;       // 2048 floats
    float* cstats = p + NPLANE;         // 4096 floats (sum, sumsq per plane)

    k_stats<<<NPLANE, 256, 0, stream>>>(x, rw, p, cstats);
    k_out  <<<NPLANE, 256, 0, stream>>>(x, w1, w2, rw, p, cstats, out);
}

// Round 4
// 282.126 us; speedup vs baseline: 1.5900x; 1.2769x over previous
//
#include <hip/hip_runtime.h>
#include <math.h>

// Problem constants: B=8, C=256, H=W=128
#define NPLANE 2048
#define HW     16384
#define WW     128
#define SLOPE  0.01f
#define EPS    1e-5f

typedef float v4f __attribute__((ext_vector_type(4)));  // native vec for nontemporal store

struct W9 { float w0,w1,w2,w3,w4,w5,w6,w7,w8; };

// Load one image row segment (4 cols) + left/right neighbors via cross-lane
// shuffle.  Lanes 0-31 of a wave span one full row (32*4=128 cols); lanes
// 32-63 span another row, so the lane-31/32 shuffle boundary coincides with
// the column zero-pad boundary -- one mask handles both.
__device__ __forceinline__ void load_row(const float* __restrict__ xp, int r,
                                         int c4, int lane32,
                                         float4& m, float& L, float& R) {
    int rc = r;
    if (rc < 0) rc = 0;
    if (rc > 127) rc = 127;
    const float va = (r == rc) ? 1.f : 0.f;        // zero-pad rows -1 / 128
    float4 v = *(const float4*)(xp + rc * WW + c4);
    m.x = v.x * va; m.y = v.y * va; m.z = v.z * va; m.w = v.w * va;
    L = __shfl_up(m.w, 1, 64);
    if (lane32 == 0) L = 0.f;                      // col -1 zero-pad
    R = __shfl_down(m.x, 1, 64);
    if (lane32 == 31) R = 0.f;                     // col 128 zero-pad
}

// ---------------------------------------------------------------------------
// Kernel A (k_mean): pure streaming plane mean -- the ONLY quantity with a
// cross-plane dependency (attention MLP needs all 256 channel means of a
// batch).  Conv statistics moved into k_out (round-3 lesson: computing the
// conv twice, once for stats and once for output, wastes a full VALU pass;
// k_out's block owns the whole plane so it can self-compute sum/sumsq).
// Trivially BW-bound: 16 independent float4 loads per thread, no shuffles,
// no weights.
// ---------------------------------------------------------------------------
__global__ __launch_bounds__(256, 8) void k_mean(const float* __restrict__ x,
                                                 float* __restrict__ p) {
    const int plane = blockIdx.x;
    const float4* xp = (const float4*)(x + (size_t)plane * HW);
    float xs = 0.f;
#pragma unroll
    for (int i = 0; i < 16; ++i) {
        float4 v = xp[i * 256 + threadIdx.x];
        xs += (v.x + v.y) + (v.z + v.w);
    }
#pragma unroll
    for (int off = 32; off; off >>= 1) xs += __shfl_down(xs, off, 64);
    __shared__ float red[4];
    if ((threadIdx.x & 63) == 0) red[threadIdx.x >> 6] = xs;
    __syncthreads();
    if (threadIdx.x == 0)
        p[plane] = ((red[0] + red[1]) + (red[2] + red[3])) * (1.f / (float)HW);
}

// ---------------------------------------------------------------------------
// Kernel B (k_out): attention MLP + ONE conv pass kept in registers +
// self-computed instance-norm stats + normalize + store.
//   out = a*(conv - mean_c) * rsqrt(a^2*var_c + eps); bias cancels exactly.
// Thread t: columns [4*(t&31), +4), rows [16*(t>>5), +16).  Conv results
// res[16] (64 VGPR) are statically indexed (FULL unroll -- partial unroll
// would scratch-spill them, round-3 lesson).  __launch_bounds__(256,4) gives
// a 128-VGPR budget; live set ~110.
// ---------------------------------------------------------------------------
__global__ __launch_bounds__(256, 4) void k_out(const float* __restrict__ x,
                                                const float* __restrict__ w1,
                                                const float* __restrict__ w2,
                                                const float* __restrict__ rw,
                                                const float* __restrict__ p,
                                                float* __restrict__ out) {
    __shared__ float hs[64];
    __shared__ float red[8];
    __shared__ float sh_a, sh_mean, sh_scale;
    const int plane = blockIdx.x;
    const int b = plane >> 8, ch = plane & 255;

    // ---- attention hidden layer: hs[j] = leaky(dot(p[b,:], w1[j,:])), 4 thr/j
    {
        const int j = threadIdx.x >> 2, part = threadIdx.x & 3;
        const float4* pr = (const float4*)(p  + b * 256 + part * 64);
        const float4* wr = (const float4*)(w1 + j * 256 + part * 64);
        float acc = 0.f;
#pragma unroll
        for (int k = 0; k < 16; ++k) {
            float4 pv = pr[k], wv = wr[k];
            acc += pv.x*wv.x + pv.y*wv.y + pv.z*wv.z + pv.w*wv.w;
        }
        acc += __shfl_xor(acc, 1, 64);
        acc += __shfl_xor(acc, 2, 64);
        if (part == 0) hs[j] = acc > 0.f ? acc : SLOPE * acc;
    }
    __syncthreads();
    // ---- attention output layer -> sigmoid gate a (stats come later)
    if (threadIdx.x < 64) {
        float v = w2[ch * 64 + threadIdx.x] * hs[threadIdx.x];
#pragma unroll
        for (int off = 32; off; off >>= 1) v += __shfl_down(v, off, 64);
        if (threadIdx.x == 0) sh_a = 1.f / (1.f + expf(-v));
    }

    const W9 w = { rw[ch*9+0], rw[ch*9+1], rw[ch*9+2],
                   rw[ch*9+3], rw[ch*9+4], rw[ch*9+5],
                   rw[ch*9+6], rw[ch*9+7], rw[ch*9+8] };

    const float* xp = x + (size_t)plane * HW;
    const int lane32 = threadIdx.x & 31;
    const int c4 = lane32 * 4;
    const int r0 = (threadIdx.x >> 5) * 16;

    // ---- conv pass: sliding 3-row window, results kept in registers
    float4 m0, m1, m2;
    float L0, R0, L1, R1, L2, R2;
    load_row(xp, r0 - 1, c4, lane32, m0, L0, R0);
    load_row(xp, r0,     c4, lane32, m1, L1, R1);

    v4f res[16];
    float s = 0.f, sq = 0.f;
#pragma unroll
    for (int j = 0; j < 16; ++j) {
        load_row(xp, r0 + j + 1, c4, lane32, m2, L2, R2);
        float o0 = w.w0*L0   + w.w1*m0.x + w.w2*m0.y
                 + w.w3*L1   + w.w4*m1.x + w.w5*m1.y
                 + w.w6*L2   + w.w7*m2.x + w.w8*m2.y;
        float o1 = w.w0*m0.x + w.w1*m0.y + w.w2*m0.z
                 + w.w3*m1.x + w.w4*m1.y + w.w5*m1.z
                 + w.w6*m2.x + w.w7*m2.y + w.w8*m2.z;
        float o2 = w.w0*m0.y + w.w1*m0.z + w.w2*m0.w
                 + w.w3*m1.y + w.w4*m1.z + w.w5*m1.w
                 + w.w6*m2.y + w.w7*m2.z + w.w8*m2.w;
        float o3 = w.w0*m0.z + w.w1*m0.w + w.w2*R0
                 + w.w3*m1.z + w.w4*m1.w + w.w5*R1
                 + w.w6*m2.z + w.w7*m2.w + w.w8*R2;
        res[j].x = o0; res[j].y = o1; res[j].z = o2; res[j].w = o3;
        s  += (o0 + o1) + (o2 + o3);
        sq += o0*o0 + o1*o1 + o2*o2 + o3*o3;
        m0 = m1; L0 = L1; R0 = R1; m1 = m2; L1 = L2; R1 = R2;
    }

    // ---- block-wide instance-norm stats over the conv results
#pragma unroll
    for (int off = 32; off; off >>= 1) {
        s  += __shfl_down(s,  off, 64);
        sq += __shfl_down(sq, off, 64);
    }
    const int wave = threadIdx.x >> 6, lane = threadIdx.x & 63;
    if (lane == 0) { red[wave] = s; red[4+wave] = sq; }
    __syncthreads();
    if (threadIdx.x == 0) {
        const float S  = (red[0]+red[1]) + (red[2]+red[3]);
        const float SQ = (red[4]+red[5]) + (red[6]+red[7]);
        const float mc = S * (1.f/(float)HW);
        const float vc = SQ * (1.f/(float)HW) - mc * mc;
        const float a  = sh_a;                // written by this same thread
        sh_mean  = mc;
        sh_scale = a * rsqrtf(a * a * vc + EPS);
    }
    __syncthreads();
    const float mean_c = sh_mean, scale = sh_scale;

    // ---- normalize registers + leaky + nontemporal store
    float* op = out + (size_t)plane * HW;
#pragma unroll
    for (int j = 0; j < 16; ++j) {
        v4f r = res[j], o;
        float t0 = scale * (r.x - mean_c); o.x = t0 > 0.f ? t0 : SLOPE * t0;
        float t1 = scale * (r.y - mean_c); o.y = t1 > 0.f ? t1 : SLOPE * t1;
        float t2 = scale * (r.z - mean_c); o.z = t2 > 0.f ? t2 : SLOPE * t2;
        float t3 = scale * (r.w - mean_c); o.w = t3 > 0.f ? t3 : SLOPE * t3;
        __builtin_nontemporal_store(o, (v4f*)(op + (r0 + j) * WW + c4));
    }
}

// ---------------------------------------------------------------------------
extern "C" void kernel_launch(void* const* d_in, const int* in_sizes, int n_in,
                              void* d_out, int out_size, void* d_ws, size_t ws_size,
                              hipStream_t stream) {
    const float* x  = (const float*)d_in[0];
    const float* w1 = (const float*)d_in[1];   // [64,256]
    const float* w2 = (const float*)d_in[2];   // [256,64]
    const float* rw = (const float*)d_in[3];   // [256,1,3,3]
    // d_in[4] (refine_b) cancels exactly in instance norm -- unused.
    float* out = (float*)d_out;

    float* p = (float*)d_ws;            // 2048 floats (per-plane means)

    k_mean<<<NPLANE, 256, 0, stream>>>(x, p);
    k_out <<<NPLANE, 256, 0, stream>>>(x, w1, w2, rw, p, out);
}

// Round 5
// 279.545 us; speedup vs baseline: 1.6047x; 1.0092x over previous
//
#include <hip/hip_runtime.h>
#include <math.h>

// Problem constants: B=8, C=256, H=W=128
#define NPLANE 2048
#define HW     16384
#define WW     128
#define SLOPE  0.01f
#define EPS    1e-5f

typedef float v4f __attribute__((ext_vector_type(4)));  // native vec for nontemporal store

struct W9 { float w0,w1,w2,w3,w4,w5,w6,w7,w8; };

// Load one image row segment (4 cols) + left/right neighbors via cross-lane
// shuffle.  Each 32-lane half-wave spans one full row (32*4=128 cols), so the
// lane-31/32 shuffle boundary coincides with the column zero-pad boundary --
// one mask handles both.
__device__ __forceinline__ void load_row(const float* __restrict__ xp, int r,
                                         int c4, int lane32,
                                         float4& m, float& L, float& R) {
    int rc = r;
    if (rc < 0) rc = 0;
    if (rc > 127) rc = 127;
    const float va = (r == rc) ? 1.f : 0.f;        // zero-pad rows -1 / 128
    float4 v = *(const float4*)(xp + rc * WW + c4);
    m.x = v.x * va; m.y = v.y * va; m.z = v.z * va; m.w = v.w * va;
    L = __shfl_up(m.w, 1, 64);
    if (lane32 == 0) L = 0.f;                      // col -1 zero-pad
    R = __shfl_down(m.x, 1, 64);
    if (lane32 == 31) R = 0.f;                     // col 128 zero-pad
}

// ---------------------------------------------------------------------------
// Kernel A (k_mean): pure streaming plane mean -- the ONLY quantity with a
// cross-plane dependency (attention MLP needs all 256 channel means of a
// batch).  Trivially BW-bound: 16 independent float4 loads/thread.
// ---------------------------------------------------------------------------
__global__ __launch_bounds__(256, 8) void k_mean(const float* __restrict__ x,
                                                 float* __restrict__ p) {
    const int plane = blockIdx.x;
    const float4* xp = (const float4*)(x + (size_t)plane * HW);
    float xs = 0.f;
#pragma unroll
    for (int i = 0; i < 16; ++i) {
        float4 v = xp[i * 256 + threadIdx.x];
        xs += (v.x + v.y) + (v.z + v.w);
    }
#pragma unroll
    for (int off = 32; off; off >>= 1) xs += __shfl_down(xs, off, 64);
    __shared__ float red[4];
    if ((threadIdx.x & 63) == 0) red[threadIdx.x >> 6] = xs;
    __syncthreads();
    if (threadIdx.x == 0)
        p[plane] = ((red[0] + red[1]) + (red[2] + red[3])) * (1.f / (float)HW);
}

// ---------------------------------------------------------------------------
// Kernel B (k_out): attention MLP + ONE conv pass kept in registers +
// self-computed instance-norm stats + normalize + store.
//   out = a*(conv - mean_c) * rsqrt(a^2*var_c + eps); bias cancels exactly.
// Round-4 lesson: res[16]@256thr cost half the occupancy (16 waves/CU) and
// the latency-bound conv pass starved.  Re-tile: 1024 threads, 4 rows/thread
// -> res[4] (16 VGPR), live set ~55 VGPR, __launch_bounds__(1024,8) = 2
// blocks/CU = 32 waves/CU (full occupancy).  Sliding window (not forced
// burst arrays -- round-3 spill lesson) leaves the allocator freedom.
// Thread t: columns [4*(t&31), +4), rows [4*(t>>5), +4).
// ---------------------------------------------------------------------------
__global__ __launch_bounds__(1024, 8) void k_out(const float* __restrict__ x,
                                                 const float* __restrict__ w1,
                                                 const float* __restrict__ w2,
                                                 const float* __restrict__ rw,
                                                 const float* __restrict__ p,
                                                 float* __restrict__ out) {
    __shared__ float hs[64];
    __shared__ float red[32];
    __shared__ float sh_a, sh_mean, sh_scale;
    const int plane = blockIdx.x;
    const int b = plane >> 8, ch = plane & 255;
    const int tid = threadIdx.x;

    // ---- attention hidden layer (first 256 threads; 4 thr per hidden unit)
    if (tid < 256) {
        const int j = tid >> 2, part = tid & 3;
        const float4* pr = (const float4*)(p  + b * 256 + part * 64);
        const float4* wr = (const float4*)(w1 + j * 256 + part * 64);
        float acc = 0.f;
#pragma unroll
        for (int k = 0; k < 16; ++k) {
            float4 pv = pr[k], wv = wr[k];
            acc += pv.x*wv.x + pv.y*wv.y + pv.z*wv.z + pv.w*wv.w;
        }
        acc += __shfl_xor(acc, 1, 64);
        acc += __shfl_xor(acc, 2, 64);
        if (part == 0) hs[j] = acc > 0.f ? acc : SLOPE * acc;
    }
    __syncthreads();
    // ---- attention output layer -> sigmoid gate a
    if (tid < 64) {
        float v = w2[ch * 64 + tid] * hs[tid];
#pragma unroll
        for (int off = 32; off; off >>= 1) v += __shfl_down(v, off, 64);
        if (tid == 0) sh_a = 1.f / (1.f + expf(-v));
    }

    const W9 w = { rw[ch*9+0], rw[ch*9+1], rw[ch*9+2],
                   rw[ch*9+3], rw[ch*9+4], rw[ch*9+5],
                   rw[ch*9+6], rw[ch*9+7], rw[ch*9+8] };

    const float* xp = x + (size_t)plane * HW;
    const int lane32 = tid & 31;
    const int c4 = lane32 * 4;
    const int r0 = (tid >> 5) * 4;

    // ---- conv pass: sliding 3-row window over 4 output rows
    float4 m0, m1, m2;
    float L0, R0, L1, R1, L2, R2;
    load_row(xp, r0 - 1, c4, lane32, m0, L0, R0);
    load_row(xp, r0,     c4, lane32, m1, L1, R1);

    v4f res[4];
    float s = 0.f, sq = 0.f;
#pragma unroll
    for (int j = 0; j < 4; ++j) {
        load_row(xp, r0 + j + 1, c4, lane32, m2, L2, R2);
        float o0 = w.w0*L0   + w.w1*m0.x + w.w2*m0.y
                 + w.w3*L1   + w.w4*m1.x + w.w5*m1.y
                 + w.w6*L2   + w.w7*m2.x + w.w8*m2.y;
        float o1 = w.w0*m0.x + w.w1*m0.y + w.w2*m0.z
                 + w.w3*m1.x + w.w4*m1.y + w.w5*m1.z
                 + w.w6*m2.x + w.w7*m2.y + w.w8*m2.z;
        float o2 = w.w0*m0.y + w.w1*m0.z + w.w2*m0.w
                 + w.w3*m1.y + w.w4*m1.z + w.w5*m1.w
                 + w.w6*m2.y + w.w7*m2.z + w.w8*m2.w;
        float o3 = w.w0*m0.z + w.w1*m0.w + w.w2*R0
                 + w.w3*m1.z + w.w4*m1.w + w.w5*R1
                 + w.w6*m2.z + w.w7*m2.w + w.w8*R2;
        res[j].x = o0; res[j].y = o1; res[j].z = o2; res[j].w = o3;
        s  += (o0 + o1) + (o2 + o3);
        sq += o0*o0 + o1*o1 + o2*o2 + o3*o3;
        m0 = m1; L0 = L1; R0 = R1; m1 = m2; L1 = L2; R1 = R2;
    }

    // ---- block-wide instance-norm stats over the conv results (16 waves)
#pragma unroll
    for (int off = 32; off; off >>= 1) {
        s  += __shfl_down(s,  off, 64);
        sq += __shfl_down(sq, off, 64);
    }
    const int wave = tid >> 6, lane = tid & 63;
    if (lane == 0) { red[wave] = s; red[16 + wave] = sq; }
    __syncthreads();
    if (tid == 0) {
        float S = 0.f, SQ = 0.f;
#pragma unroll
        for (int i = 0; i < 16; ++i) { S += red[i]; SQ += red[16 + i]; }
        const float mc = S * (1.f/(float)HW);
        const float vc = SQ * (1.f/(float)HW) - mc * mc;
        const float a  = sh_a;                // written by this same thread
        sh_mean  = mc;
        sh_scale = a * rsqrtf(a * a * vc + EPS);
    }
    __syncthreads();
    const float mean_c = sh_mean, scale = sh_scale;

    // ---- normalize registers + leaky + nontemporal store
    float* op = out + (size_t)plane * HW;
#pragma unroll
    for (int j = 0; j < 4; ++j) {
        v4f r = res[j], o;
        float t0 = scale * (r.x - mean_c); o.x = t0 > 0.f ? t0 : SLOPE * t0;
        float t1 = scale * (r.y - mean_c); o.y = t1 > 0.f ? t1 : SLOPE * t1;
        float t2 = scale * (r.z - mean_c); o.z = t2 > 0.f ? t2 : SLOPE * t2;
        float t3 = scale * (r.w - mean_c); o.w = t3 > 0.f ? t3 : SLOPE * t3;
        __builtin_nontemporal_store(o, (v4f*)(op + (r0 + j) * WW + c4));
    }
}

// ---------------------------------------------------------------------------
extern "C" void kernel_launch(void* const* d_in, const int* in_sizes, int n_in,
                              void* d_out, int out_size, void* d_ws, size_t ws_size,
                              hipStream_t stream) {
    const float* x  = (const float*)d_in[0];
    const float* w1 = (const float*)d_in[1];   // [64,256]
    const float* w2 = (const float*)d_in[2];   // [256,64]
    const float* rw = (const float*)d_in[3];   // [256,1,3,3]
    // d_in[4] (refine_b) cancels exactly in instance norm -- unused.
    float* out = (float*)d_out;

    float* p = (float*)d_ws;            // 2048 floats (per-plane means)

    k_mean<<<NPLANE, 256,  0, stream>>>(x, p);
    k_out <<<NPLANE, 1024, 0, stream>>>(x, w1, w2, rw, p, out);
}